// Round 4
// baseline (191.665 us; speedup 1.0000x reference)
//
#include <hip/hip_runtime.h>
#include <math.h>

// Problem constants (match reference)
#define B_ 2048
#define L_ 200
#define V_ 50000
#define D_ 300
#define H_ 128
#define C_ 20

// -----------------------------------------------------------------------------
// Fully fused kernel: one block (256 threads) per batch row.
//   Phase A: embedding gather + sum/max reduce. 225 lanes = 3 L-groups x 75
//            float4-quads, coalesced 16B/lane. Explicit 4-deep load batching:
//            R1 counters (VGPR=20, VALUBusy 8%, 3.45 TB/s) showed the compiler
//            kept only ~2 gathers in flight -> latency-bound. 4 indices read,
//            4 global_load_dwordx4 issued, then accumulate.
//   Phase B: h = relu(W_new @ rep + b_new). Lane map: c = t>>2 (+64*pass),
//            k-quad = (t&3) + 4i -> wave reads 16 cols x 4 consecutive quads
//            = 16 fully-consumed 64B lines per instr; 4-lane __shfl_xor.
//   Phase C: out = h @ W3^T + b3 (20 outputs, W3 L1-hot).
// MLP tail hides under other co-resident blocks' gather stalls.
// -----------------------------------------------------------------------------
__global__ __launch_bounds__(256, 4) void fused_dnn_kernel(
    const int* __restrict__ x,        // [B][L]
    const int* __restrict__ lengths,  // [B]
    const float* __restrict__ emb,    // [V][D]
    const float* __restrict__ W_new,  // [H][2D]
    const float* __restrict__ b_new,  // [H]
    const float* __restrict__ W3,     // [C][H]
    const float* __restrict__ b3,     // [C]
    float* __restrict__ out)          // [B][C]
{
    __shared__ int    s_idx[L_];
    __shared__ float4 s_sum[225];
    __shared__ float4 s_max[225];
    __shared__ float4 s_rep4[150];    // [0..75) mean_bug quads, [75..150) max quads
    __shared__ float  s_h[H_];

    const int b = blockIdx.x;
    const int t = threadIdx.x;

    // ---- Phase A: gather + reduce ----
    if (t < L_) s_idx[t] = x[b * L_ + t];
    __syncthreads();

    if (t < 225) {
        const int g = t / 75;       // 0..2
        const int p = t - g * 75;   // 0..74
        const int col = p << 2;
        float4 s4 = make_float4(0.f, 0.f, 0.f, 0.f);
        float4 m4 = make_float4(-INFINITY, -INFINITY, -INFINITY, -INFINITY);

        int l = g;
        // 4-deep batched main loop: 4 independent gathers in flight.
        for (; l + 9 < L_; l += 12) {
            const size_t r0 = (size_t)s_idx[l    ] * D_;
            const size_t r1 = (size_t)s_idx[l + 3] * D_;
            const size_t r2 = (size_t)s_idx[l + 6] * D_;
            const size_t r3 = (size_t)s_idx[l + 9] * D_;
            const float4 v0 = *(const float4*)(emb + r0 + col);
            const float4 v1 = *(const float4*)(emb + r1 + col);
            const float4 v2 = *(const float4*)(emb + r2 + col);
            const float4 v3 = *(const float4*)(emb + r3 + col);
            s4.x += v0.x; s4.y += v0.y; s4.z += v0.z; s4.w += v0.w;
            m4.x = fmaxf(m4.x, v0.x); m4.y = fmaxf(m4.y, v0.y);
            m4.z = fmaxf(m4.z, v0.z); m4.w = fmaxf(m4.w, v0.w);
            s4.x += v1.x; s4.y += v1.y; s4.z += v1.z; s4.w += v1.w;
            m4.x = fmaxf(m4.x, v1.x); m4.y = fmaxf(m4.y, v1.y);
            m4.z = fmaxf(m4.z, v1.z); m4.w = fmaxf(m4.w, v1.w);
            s4.x += v2.x; s4.y += v2.y; s4.z += v2.z; s4.w += v2.w;
            m4.x = fmaxf(m4.x, v2.x); m4.y = fmaxf(m4.y, v2.y);
            m4.z = fmaxf(m4.z, v2.z); m4.w = fmaxf(m4.w, v2.w);
            s4.x += v3.x; s4.y += v3.y; s4.z += v3.z; s4.w += v3.w;
            m4.x = fmaxf(m4.x, v3.x); m4.y = fmaxf(m4.y, v3.y);
            m4.z = fmaxf(m4.z, v3.z); m4.w = fmaxf(m4.w, v3.w);
        }
        // remainder (<= 3 rows)
        for (; l < L_; l += 3) {
            const float4 v =
                *(const float4*)(emb + (size_t)s_idx[l] * D_ + col);
            s4.x += v.x; s4.y += v.y; s4.z += v.z; s4.w += v.w;
            m4.x = fmaxf(m4.x, v.x); m4.y = fmaxf(m4.y, v.y);
            m4.z = fmaxf(m4.z, v.z); m4.w = fmaxf(m4.w, v.w);
        }
        s_sum[t] = s4;
        s_max[t] = m4;
    }
    __syncthreads();

    if (t < 75) {
        const float4 sa = s_sum[t], sb = s_sum[t + 75], sc = s_sum[t + 150];
        const float4 ma = s_max[t], mb = s_max[t + 75], mc = s_max[t + 150];
        const float lf = (float)lengths[b];
        const float inv = 1.0f / (lf * lf);   // reference bug: sum / len^2
        float4 S, M;
        S.x = (sa.x + sb.x + sc.x) * inv;
        S.y = (sa.y + sb.y + sc.y) * inv;
        S.z = (sa.z + sb.z + sc.z) * inv;
        S.w = (sa.w + sb.w + sc.w) * inv;
        M.x = fmaxf(fmaxf(ma.x, mb.x), mc.x);
        M.y = fmaxf(fmaxf(ma.y, mb.y), mc.y);
        M.z = fmaxf(fmaxf(ma.z, mb.z), mc.z);
        M.w = fmaxf(fmaxf(ma.w, mb.w), mc.w);
        s_rep4[t]      = S;   // mean_bug, d = 4t..4t+3
        s_rep4[75 + t] = M;   // max,      d = 300+4t..300+4t+3
    }
    __syncthreads();

    // ---- Phase B: h = relu(W_new @ rep + b_new) ----
    // Full 600-float dot = 150 float4 quads (150 = 4*37 + 2).
    {
        const int lane2 = t & 3;    // k-subgroup within 4-lane cluster
        const int cbase = t >> 2;   // 0..63

        #pragma unroll
        for (int pass = 0; pass < 2; ++pass) {
            const int c = cbase + (pass << 6);
            const float4* wrow = (const float4*)(W_new + (size_t)c * (2 * D_));
            float acc = 0.f;
            #pragma unroll 4
            for (int i = 0; i < 38; ++i) {
                const int q = lane2 + (i << 2);
                if (q < 150) {   // always true for i<=36; runtime only at i=37
                    const float4 w = wrow[q];
                    const float4 r = s_rep4[q];
                    acc = fmaf(w.x, r.x, acc);
                    acc = fmaf(w.y, r.y, acc);
                    acc = fmaf(w.z, r.z, acc);
                    acc = fmaf(w.w, r.w, acc);
                }
            }
            // combine the 4 k-subgroups (same wave: lanes differ in bits 0..1)
            acc += __shfl_xor(acc, 1);
            acc += __shfl_xor(acc, 2);
            if (lane2 == 0) {
                s_h[c] = fmaxf(acc + b_new[c], 0.f);
            }
        }
    }
    __syncthreads();

    // ---- Phase C: out = h @ W3^T + b3 ----
    if (t < C_) {
        const float* w3 = W3 + t * H_;
        float acc = b3[t];
        #pragma unroll 16
        for (int k = 0; k < H_; ++k) acc = fmaf(s_h[k], w3[k], acc);
        out[(size_t)b * C_ + t] = acc;
    }
}

// -----------------------------------------------------------------------------
extern "C" void kernel_launch(void* const* d_in, const int* in_sizes, int n_in,
                              void* d_out, int out_size, void* d_ws, size_t ws_size,
                              hipStream_t stream) {
    const int*   x       = (const int*)  d_in[0];
    const int*   lengths = (const int*)  d_in[1];
    const float* emb     = (const float*)d_in[2];
    const float* W_new   = (const float*)d_in[3];
    const float* b_new   = (const float*)d_in[4];
    const float* W3      = (const float*)d_in[5];
    const float* b3      = (const float*)d_in[6];
    float* out = (float*)d_out;

    fused_dnn_kernel<<<B_, 256, 0, stream>>>(x, lengths, emb, W_new, b_new, W3, b3, out);
}

// Round 5
// 180.928 us; speedup vs baseline: 1.0593x; 1.0593x over previous
//
#include <hip/hip_runtime.h>
#include <math.h>

// Problem constants (match reference)
#define B_ 2048
#define L_ 200
#define V_ 50000
#define D_ 300
#define H_ 128
#define C_ 20

// -----------------------------------------------------------------------------
// Kernel 1: per-batch-row embedding gather + sum/max (R1-proven: 72 us,
// 3.45 TB/s, BW-bound). One block per batch row; 225 lanes = 3 L-groups x 75
// float4-quads, coalesced 16B/lane. Writes rep[b][0:300]=sum/len^2 (reference
// bug preserved), rep[b][300:600]=max.
// -----------------------------------------------------------------------------
__global__ __launch_bounds__(256, 4) void gather_reduce_kernel(
    const int* __restrict__ x,        // [B][L]
    const int* __restrict__ lengths,  // [B]
    const float* __restrict__ emb,    // [V][D]
    float* __restrict__ rep)          // [B][2D]
{
    __shared__ int s_idx[L_];
    __shared__ float4 s_sum[225];
    __shared__ float4 s_max[225];

    const int b = blockIdx.x;
    const int t = threadIdx.x;

    if (t < L_) s_idx[t] = x[b * L_ + t];
    __syncthreads();

    if (t < 225) {
        const int g = t / 75;       // 0..2
        const int p = t - g * 75;   // 0..74
        float4 s4 = make_float4(0.f, 0.f, 0.f, 0.f);
        float4 m4 = make_float4(-INFINITY, -INFINITY, -INFINITY, -INFINITY);
        #pragma unroll 4
        for (int l = g; l < L_; l += 3) {
            const float4 v =
                *(const float4*)(emb + (size_t)s_idx[l] * D_ + (p << 2));
            s4.x += v.x; s4.y += v.y; s4.z += v.z; s4.w += v.w;
            m4.x = fmaxf(m4.x, v.x); m4.y = fmaxf(m4.y, v.y);
            m4.z = fmaxf(m4.z, v.z); m4.w = fmaxf(m4.w, v.w);
        }
        s_sum[t] = s4;
        s_max[t] = m4;
    }
    __syncthreads();

    if (t < 75) {
        const float4 sa = s_sum[t], sb = s_sum[t + 75], sc = s_sum[t + 150];
        const float4 ma = s_max[t], mb = s_max[t + 75], mc = s_max[t + 150];
        const float lf = (float)lengths[b];
        const float inv = 1.0f / (lf * lf);   // reference bug: sum / len^2
        float4 S, M;
        S.x = (sa.x + sb.x + sc.x) * inv;
        S.y = (sa.y + sb.y + sc.y) * inv;
        S.z = (sa.z + sb.z + sc.z) * inv;
        S.w = (sa.w + sb.w + sc.w) * inv;
        M.x = fmaxf(fmaxf(ma.x, mb.x), mc.x);
        M.y = fmaxf(fmaxf(ma.y, mb.y), mc.y);
        M.z = fmaxf(fmaxf(ma.z, mb.z), mc.z);
        M.w = fmaxf(fmaxf(ma.w, mb.w), mc.w);
        float4* o = (float4*)(rep + (size_t)b * (2 * D_));
        o[t]      = S;   // mean_bug part, d = 4t..4t+3
        o[75 + t] = M;   // max part, d = 300+4t..300+4t+3
    }
}

// -----------------------------------------------------------------------------
// Kernel 2: row-tiled fused MLP. 256 blocks x 8 rows. Lane map: 4-lane cluster
// (lane2 = t&3) owns cols c and c+64 (c = t>>2); per W-quad load the cluster
// accumulates all 8 rows (rep quads broadcast from LDS, conflict-free).
// W_new read once per 8 rows -> 256 * 307KB = 79 MB L2 traffic (~2 us).
// 4-lane __shfl_xor combine; Phase C (20 cols) trivial, W3 L1-hot.
// -----------------------------------------------------------------------------
__global__ __launch_bounds__(256) void mlp8_kernel(
    const float* __restrict__ rep,    // [B][2D]
    const float* __restrict__ W_new,  // [H][2D]
    const float* __restrict__ b_new,  // [H]
    const float* __restrict__ W3,     // [C][H]
    const float* __restrict__ b3,     // [C]
    float* __restrict__ out)          // [B][C]
{
    __shared__ float4 s_rep[8][150];      // 19.2 KB
    __shared__ float  s_h[8][H_ + 4];     // padded

    const int t = threadIdx.x;
    const int row0 = blockIdx.x * 8;

    // Stage 8 rep rows (contiguous 4800 floats = 1200 float4), coalesced.
    {
        const float4* src = (const float4*)(rep + (size_t)row0 * (2 * D_));
        float4* dst = (float4*)&s_rep[0][0];
        #pragma unroll
        for (int i = 0; i < 5; ++i) {
            const int j = t + (i << 8);
            if (j < 1200) dst[j] = src[j];   // 1200 = 4*256 + 176
        }
    }
    __syncthreads();

    // ---- Layer 1: h = relu(W_new @ rep + b_new) ----
    const int lane2 = t & 3;    // k-subgroup within 4-lane cluster
    const int c0 = t >> 2;      // 0..63
    const int c1 = c0 + 64;

    float acc0[8] = {0.f, 0.f, 0.f, 0.f, 0.f, 0.f, 0.f, 0.f};
    float acc1[8] = {0.f, 0.f, 0.f, 0.f, 0.f, 0.f, 0.f, 0.f};

    const float4* w0row = (const float4*)(W_new + (size_t)c0 * (2 * D_));
    const float4* w1row = (const float4*)(W_new + (size_t)c1 * (2 * D_));

    #pragma unroll 2
    for (int i = 0; i < 38; ++i) {
        const int q = lane2 + (i << 2);
        if (q < 150) {   // always true for i<=36; runtime only at i=37
            const float4 w0 = w0row[q];
            const float4 w1 = w1row[q];
            #pragma unroll
            for (int r = 0; r < 8; ++r) {
                const float4 rq = s_rep[r][q];
                acc0[r] = fmaf(w0.x, rq.x, acc0[r]);
                acc0[r] = fmaf(w0.y, rq.y, acc0[r]);
                acc0[r] = fmaf(w0.z, rq.z, acc0[r]);
                acc0[r] = fmaf(w0.w, rq.w, acc0[r]);
                acc1[r] = fmaf(w1.x, rq.x, acc1[r]);
                acc1[r] = fmaf(w1.y, rq.y, acc1[r]);
                acc1[r] = fmaf(w1.z, rq.z, acc1[r]);
                acc1[r] = fmaf(w1.w, rq.w, acc1[r]);
            }
        }
    }

    // combine the 4 k-subgroups (lanes differ in bits 0..1 -> same wave)
    const float bn0 = b_new[c0];
    const float bn1 = b_new[c1];
    #pragma unroll
    for (int r = 0; r < 8; ++r) {
        float a0 = acc0[r];
        a0 += __shfl_xor(a0, 1);
        a0 += __shfl_xor(a0, 2);
        float a1 = acc1[r];
        a1 += __shfl_xor(a1, 1);
        a1 += __shfl_xor(a1, 2);
        if (lane2 == 0) {
            s_h[r][c0] = fmaxf(a0 + bn0, 0.f);
            s_h[r][c1] = fmaxf(a1 + bn1, 0.f);
        }
    }
    __syncthreads();

    // ---- Layer 2: out = h @ W3^T + b3 (8 rows x 20 cols = 160 outputs) ----
    if (t < 8 * C_) {
        const int r = t / C_;
        const int c = t - r * C_;
        const float* hr = s_h[r];
        const float* w3 = W3 + c * H_;
        float acc = b3[c];
        #pragma unroll 8
        for (int k = 0; k < H_; ++k) acc = fmaf(hr[k], w3[k], acc);
        out[(size_t)(row0 + r) * C_ + c] = acc;
    }
}

// -----------------------------------------------------------------------------
extern "C" void kernel_launch(void* const* d_in, const int* in_sizes, int n_in,
                              void* d_out, int out_size, void* d_ws, size_t ws_size,
                              hipStream_t stream) {
    const int*   x       = (const int*)  d_in[0];
    const int*   lengths = (const int*)  d_in[1];
    const float* emb     = (const float*)d_in[2];
    const float* W_new   = (const float*)d_in[3];
    const float* b_new   = (const float*)d_in[4];
    const float* W3      = (const float*)d_in[5];
    const float* b3      = (const float*)d_in[6];
    float* out = (float*)d_out;
    float* rep = (float*)d_ws;   // [B][600] = 4.92 MB scratch

    gather_reduce_kernel<<<B_, 256, 0, stream>>>(x, lengths, emb, rep);
    mlp8_kernel<<<B_ / 8, 256, 0, stream>>>(rep, W_new, b_new, W3, b3, out);
}

// Round 6
// 177.797 us; speedup vs baseline: 1.0780x; 1.0176x over previous
//
#include <hip/hip_runtime.h>
#include <math.h>

// Problem constants (match reference)
#define B_ 2048
#define L_ 200
#define V_ 50000
#define D_ 300
#define H_ 128
#define C_ 20

// -----------------------------------------------------------------------------
// Kernel 1: per-batch-row embedding gather + sum/max (R1/R5-proven: ~73 us,
// 3.5 TB/s fabric-bound). One block per batch row; 225 lanes = 3 L-groups x 75
// float4-quads, coalesced 16B/lane. Writes rep[b][0:300]=sum/len^2 (reference
// bug preserved), rep[b][300:600]=max. UNCHANGED from R5.
// -----------------------------------------------------------------------------
__global__ __launch_bounds__(256, 4) void gather_reduce_kernel(
    const int* __restrict__ x,        // [B][L]
    const int* __restrict__ lengths,  // [B]
    const float* __restrict__ emb,    // [V][D]
    float* __restrict__ rep)          // [B][2D]
{
    __shared__ int s_idx[L_];
    __shared__ float4 s_sum[225];
    __shared__ float4 s_max[225];

    const int b = blockIdx.x;
    const int t = threadIdx.x;

    if (t < L_) s_idx[t] = x[b * L_ + t];
    __syncthreads();

    if (t < 225) {
        const int g = t / 75;       // 0..2
        const int p = t - g * 75;   // 0..74
        float4 s4 = make_float4(0.f, 0.f, 0.f, 0.f);
        float4 m4 = make_float4(-INFINITY, -INFINITY, -INFINITY, -INFINITY);
        #pragma unroll 4
        for (int l = g; l < L_; l += 3) {
            const float4 v =
                *(const float4*)(emb + (size_t)s_idx[l] * D_ + (p << 2));
            s4.x += v.x; s4.y += v.y; s4.z += v.z; s4.w += v.w;
            m4.x = fmaxf(m4.x, v.x); m4.y = fmaxf(m4.y, v.y);
            m4.z = fmaxf(m4.z, v.z); m4.w = fmaxf(m4.w, v.w);
        }
        s_sum[t] = s4;
        s_max[t] = m4;
    }
    __syncthreads();

    if (t < 75) {
        const float4 sa = s_sum[t], sb = s_sum[t + 75], sc = s_sum[t + 150];
        const float4 ma = s_max[t], mb = s_max[t + 75], mc = s_max[t + 150];
        const float lf = (float)lengths[b];
        const float inv = 1.0f / (lf * lf);   // reference bug: sum / len^2
        float4 S, M;
        S.x = (sa.x + sb.x + sc.x) * inv;
        S.y = (sa.y + sb.y + sc.y) * inv;
        S.z = (sa.z + sb.z + sc.z) * inv;
        S.w = (sa.w + sb.w + sc.w) * inv;
        M.x = fmaxf(fmaxf(ma.x, mb.x), mc.x);
        M.y = fmaxf(fmaxf(ma.y, mb.y), mc.y);
        M.z = fmaxf(fmaxf(ma.z, mb.z), mc.z);
        M.w = fmaxf(fmaxf(ma.w, mb.w), mc.w);
        float4* o = (float4*)(rep + (size_t)b * (2 * D_));
        o[t]      = S;   // mean_bug part, d = 4t..4t+3
        o[75 + t] = M;   // max part, d = 300+4t..300+4t+3
    }
}

// -----------------------------------------------------------------------------
// Kernel 2 (v3): row-tiled fused MLP with real TLP.
// 256 blocks x 512 threads (8 waves/CU = 2 waves/SIMD; R5's 256-thr version
// was 1 wave/SIMD and exposed the full W-load L2 latency -> inferred ~25 us).
// Each 4-lane cluster (lane2 = t&3) owns ONE col c = t>>2 (0..127); per thread
// 8 row-accumulators. Per iter: 1 W-quad load + 8 broadcast LDS reads +
// 32 FMA -> load latency hidden by issue stream + 2 waves/SIMD.
// W_new read once per block: 256 * 307KB = 79 MB L2 (~2.5 us).
// -----------------------------------------------------------------------------
__global__ __launch_bounds__(512) void mlp8_kernel(
    const float* __restrict__ rep,    // [B][2D]
    const float* __restrict__ W_new,  // [H][2D]
    const float* __restrict__ b_new,  // [H]
    const float* __restrict__ W3,     // [C][H]
    const float* __restrict__ b3,     // [C]
    float* __restrict__ out)          // [B][C]
{
    __shared__ float4 s_rep[8][150];      // 19.2 KB
    __shared__ float  s_h[8][H_ + 4];     // padded

    const int t = threadIdx.x;
    const int row0 = blockIdx.x * 8;

    // Stage 8 rep rows (contiguous 4800 floats = 1200 float4), coalesced.
    {
        const float4* src = (const float4*)(rep + (size_t)row0 * (2 * D_));
        float4* dst = (float4*)&s_rep[0][0];
        #pragma unroll
        for (int i = 0; i < 3; ++i) {
            const int j = t + (i << 9);
            if (j < 1200) dst[j] = src[j];   // 1200 = 2*512 + 176
        }
    }
    __syncthreads();

    // ---- Layer 1: h = relu(W_new @ rep + b_new) ----
    const int lane2 = t & 3;    // k-subgroup within 4-lane cluster
    const int c = t >> 2;       // col 0..127

    float acc[8] = {0.f, 0.f, 0.f, 0.f, 0.f, 0.f, 0.f, 0.f};
    const float4* wrow = (const float4*)(W_new + (size_t)c * (2 * D_));

    #pragma unroll 2
    for (int i = 0; i < 38; ++i) {
        const int q = lane2 + (i << 2);
        if (q < 150) {   // always true for i<=36; runtime only at i=37
            const float4 w = wrow[q];
            #pragma unroll
            for (int r = 0; r < 8; ++r) {
                const float4 rq = s_rep[r][q];
                acc[r] = fmaf(w.x, rq.x, acc[r]);
                acc[r] = fmaf(w.y, rq.y, acc[r]);
                acc[r] = fmaf(w.z, rq.z, acc[r]);
                acc[r] = fmaf(w.w, rq.w, acc[r]);
            }
        }
    }

    // combine the 4 k-subgroups (lanes differ in bits 0..1 -> same wave)
    const float bn = b_new[c];
    #pragma unroll
    for (int r = 0; r < 8; ++r) {
        float a = acc[r];
        a += __shfl_xor(a, 1);
        a += __shfl_xor(a, 2);
        if (lane2 == 0) s_h[r][c] = fmaxf(a + bn, 0.f);
    }
    __syncthreads();

    // ---- Layer 2: out = h @ W3^T + b3 (8 rows x 20 cols = 160 outputs) ----
    if (t < 8 * C_) {
        const int r = t / C_;
        const int cc = t - r * C_;
        const float* hr = s_h[r];
        const float4* w3 = (const float4*)(W3 + cc * H_);
        const float4* h4 = (const float4*)hr;
        float acc2 = b3[cc];
        #pragma unroll 8
        for (int k = 0; k < 32; ++k) {
            const float4 wv = w3[k];
            const float4 hv = h4[k];
            acc2 = fmaf(hv.x, wv.x, acc2);
            acc2 = fmaf(hv.y, wv.y, acc2);
            acc2 = fmaf(hv.z, wv.z, acc2);
            acc2 = fmaf(hv.w, wv.w, acc2);
        }
        out[(size_t)(row0 + r) * C_ + cc] = acc2;
    }
}

// -----------------------------------------------------------------------------
extern "C" void kernel_launch(void* const* d_in, const int* in_sizes, int n_in,
                              void* d_out, int out_size, void* d_ws, size_t ws_size,
                              hipStream_t stream) {
    const int*   x       = (const int*)  d_in[0];
    const int*   lengths = (const int*)  d_in[1];
    const float* emb     = (const float*)d_in[2];
    const float* W_new   = (const float*)d_in[3];
    const float* b_new   = (const float*)d_in[4];
    const float* W3      = (const float*)d_in[5];
    const float* b3      = (const float*)d_in[6];
    float* out = (float*)d_out;
    float* rep = (float*)d_ws;   // [B][600] = 4.92 MB scratch

    gather_reduce_kernel<<<B_, 256, 0, stream>>>(x, lengths, emb, rep);
    mlp8_kernel<<<B_ / 8, 512, 0, stream>>>(rep, W_new, b_new, W3, b3, out);
}

// Round 8
// 176.100 us; speedup vs baseline: 1.0884x; 1.0096x over previous
//
#include <hip/hip_runtime.h>
#include <math.h>

// Problem constants (match reference)
#define B_ 2048
#define L_ 200
#define V_ 50000
#define D_ 300
#define H_ 128
#define C_ 20

// -----------------------------------------------------------------------------
// Kernel 1: per-batch-row embedding gather + sum/max (R1/R5/R6-proven: ~73 us,
// 3.5 TB/s L2-miss plateau, throughput-bound; logical bytes irreducible).
// One block per batch row; 225 lanes = 3 L-groups x 75 float4-quads,
// coalesced 16B/lane. Writes rep[b][0:300]=sum/len^2 (reference bug
// preserved), rep[b][300:600]=max. UNCHANGED (control).
// -----------------------------------------------------------------------------
__global__ __launch_bounds__(256, 4) void gather_reduce_kernel(
    const int* __restrict__ x,        // [B][L]
    const int* __restrict__ lengths,  // [B]
    const float* __restrict__ emb,    // [V][D]
    float* __restrict__ rep)          // [B][2D]
{
    __shared__ int s_idx[L_];
    __shared__ float4 s_sum[225];
    __shared__ float4 s_max[225];

    const int b = blockIdx.x;
    const int t = threadIdx.x;

    if (t < L_) s_idx[t] = x[b * L_ + t];
    __syncthreads();

    if (t < 225) {
        const int g = t / 75;       // 0..2
        const int p = t - g * 75;   // 0..74
        float4 s4 = make_float4(0.f, 0.f, 0.f, 0.f);
        float4 m4 = make_float4(-INFINITY, -INFINITY, -INFINITY, -INFINITY);
        #pragma unroll 4
        for (int l = g; l < L_; l += 3) {
            const float4 v =
                *(const float4*)(emb + (size_t)s_idx[l] * D_ + (p << 2));
            s4.x += v.x; s4.y += v.y; s4.z += v.z; s4.w += v.w;
            m4.x = fmaxf(m4.x, v.x); m4.y = fmaxf(m4.y, v.y);
            m4.z = fmaxf(m4.z, v.z); m4.w = fmaxf(m4.w, v.w);
        }
        s_sum[t] = s4;
        s_max[t] = m4;
    }
    __syncthreads();

    if (t < 75) {
        const float4 sa = s_sum[t], sb = s_sum[t + 75], sc = s_sum[t + 150];
        const float4 ma = s_max[t], mb = s_max[t + 75], mc = s_max[t + 150];
        const float lf = (float)lengths[b];
        const float inv = 1.0f / (lf * lf);   // reference bug: sum / len^2
        float4 S, M;
        S.x = (sa.x + sb.x + sc.x) * inv;
        S.y = (sa.y + sb.y + sc.y) * inv;
        S.z = (sa.z + sb.z + sc.z) * inv;
        S.w = (sa.w + sb.w + sc.w) * inv;
        M.x = fmaxf(fmaxf(ma.x, mb.x), mc.x);
        M.y = fmaxf(fmaxf(ma.y, mb.y), mc.y);
        M.z = fmaxf(fmaxf(ma.z, mb.z), mc.z);
        M.w = fmaxf(fmaxf(ma.w, mb.w), mc.w);
        float4* o = (float4*)(rep + (size_t)b * (2 * D_));
        o[t]      = S;   // mean_bug part, d = 4t..4t+3
        o[75 + t] = M;   // max part, d = 300+4t..300+4t+3
    }
}

// -----------------------------------------------------------------------------
// Kernel 2 (v4): row-tiled fused MLP, LDS-traffic-reduced.
// 256 blocks x 512 threads, 8 rows/block. 16-lane k-cluster (lane16 = t&15),
// cluster cg = t>>4 (0..31) owns 4 cols {cg, cg+32, cg+64, cg+96}.
// Per K-step (10 steps of 16 quads): 4 coalesced W-quad loads (256B/group,
// W read exactly once per block = 79 MB L2 total) + 8 rep LDS reads REUSED
// across 4 cols (4x less LDS traffic than v3: 637->160 MB) + 128 FMA.
// Combine via __shfl_xor 1/2/4/8 (inside 16-lane group).
// -----------------------------------------------------------------------------
__global__ __launch_bounds__(512) void mlp8_kernel(
    const float* __restrict__ rep,    // [B][2D]
    const float* __restrict__ W_new,  // [H][2D]
    const float* __restrict__ b_new,  // [H]
    const float* __restrict__ W3,     // [C][H]
    const float* __restrict__ b3,     // [C]
    float* __restrict__ out)          // [B][C]
{
    __shared__ float4 s_rep[8][150];      // 19.2 KB
    __shared__ float  s_h[8][H_ + 4];     // padded

    const int t = threadIdx.x;
    const int row0 = blockIdx.x * 8;

    // Stage 8 rep rows (contiguous 4800 floats = 1200 float4), coalesced.
    {
        const float4* src = (const float4*)(rep + (size_t)row0 * (2 * D_));
        float4* dst = (float4*)&s_rep[0][0];
        #pragma unroll
        for (int i = 0; i < 3; ++i) {
            const int j = t + (i << 9);
            if (j < 1200) dst[j] = src[j];   // 1200 = 2*512 + 176
        }
    }
    __syncthreads();

    // ---- Layer 1: h = relu(W_new @ rep + b_new) ----
    const int lane16 = t & 15;   // k-subgroup within 16-lane cluster
    const int cg = t >> 4;       // cluster 0..31

    // acc[j][r]: col cg+32j, row r. All indexing compile-time (full unroll).
    float acc[4][8];
    #pragma unroll
    for (int j = 0; j < 4; ++j)
        #pragma unroll
        for (int r = 0; r < 8; ++r) acc[j][r] = 0.f;

    const float4* w0 = (const float4*)(W_new + (size_t)(cg     ) * (2 * D_));
    const float4* w1 = (const float4*)(W_new + (size_t)(cg + 32) * (2 * D_));
    const float4* w2 = (const float4*)(W_new + (size_t)(cg + 64) * (2 * D_));
    const float4* w3r = (const float4*)(W_new + (size_t)(cg + 96) * (2 * D_));

    #pragma unroll
    for (int i = 0; i < 10; ++i) {
        const int q = lane16 + (i << 4);
        if (q < 150) {   // compile-time true for i<9; runtime only at i=9
            const float4 wa = w0[q];
            const float4 wb = w1[q];
            const float4 wc = w2[q];
            const float4 wd = w3r[q];
            #pragma unroll
            for (int r = 0; r < 8; ++r) {
                const float4 rq = s_rep[r][q];
                acc[0][r] = fmaf(wa.x, rq.x, acc[0][r]);
                acc[0][r] = fmaf(wa.y, rq.y, acc[0][r]);
                acc[0][r] = fmaf(wa.z, rq.z, acc[0][r]);
                acc[0][r] = fmaf(wa.w, rq.w, acc[0][r]);
                acc[1][r] = fmaf(wb.x, rq.x, acc[1][r]);
                acc[1][r] = fmaf(wb.y, rq.y, acc[1][r]);
                acc[1][r] = fmaf(wb.z, rq.z, acc[1][r]);
                acc[1][r] = fmaf(wb.w, rq.w, acc[1][r]);
                acc[2][r] = fmaf(wc.x, rq.x, acc[2][r]);
                acc[2][r] = fmaf(wc.y, rq.y, acc[2][r]);
                acc[2][r] = fmaf(wc.z, rq.z, acc[2][r]);
                acc[2][r] = fmaf(wc.w, rq.w, acc[2][r]);
                acc[3][r] = fmaf(wd.x, rq.x, acc[3][r]);
                acc[3][r] = fmaf(wd.y, rq.y, acc[3][r]);
                acc[3][r] = fmaf(wd.z, rq.z, acc[3][r]);
                acc[3][r] = fmaf(wd.w, rq.w, acc[3][r]);
            }
        }
    }

    // combine the 16 k-subgroups (xor 1/2/4/8 stays inside 16-lane group)
    #pragma unroll
    for (int j = 0; j < 4; ++j) {
        const int c = cg + (j << 5);
        const float bn = b_new[c];
        #pragma unroll
        for (int r = 0; r < 8; ++r) {
            float a = acc[j][r];
            a += __shfl_xor(a, 1);
            a += __shfl_xor(a, 2);
            a += __shfl_xor(a, 4);
            a += __shfl_xor(a, 8);
            if (lane16 == 0) s_h[r][c] = fmaxf(a + bn, 0.f);
        }
    }
    __syncthreads();

    // ---- Layer 2: out = h @ W3^T + b3 (8 rows x 20 cols = 160 outputs) ----
    if (t < 8 * C_) {
        const int r = t / C_;
        const int cc = t - r * C_;
        const float* hr = s_h[r];
        const float4* w3 = (const float4*)(W3 + cc * H_);
        const float4* h4 = (const float4*)hr;
        float acc2 = b3[cc];
        #pragma unroll 8
        for (int k = 0; k < 32; ++k) {
            const float4 wv = w3[k];
            const float4 hv = h4[k];
            acc2 = fmaf(hv.x, wv.x, acc2);
            acc2 = fmaf(hv.y, wv.y, acc2);
            acc2 = fmaf(hv.z, wv.z, acc2);
            acc2 = fmaf(hv.w, wv.w, acc2);
        }
        out[(size_t)(row0 + r) * C_ + cc] = acc2;
    }
}

// -----------------------------------------------------------------------------
extern "C" void kernel_launch(void* const* d_in, const int* in_sizes, int n_in,
                              void* d_out, int out_size, void* d_ws, size_t ws_size,
                              hipStream_t stream) {
    const int*   x       = (const int*)  d_in[0];
    const int*   lengths = (const int*)  d_in[1];
    const float* emb     = (const float*)d_in[2];
    const float* W_new   = (const float*)d_in[3];
    const float* b_new   = (const float*)d_in[4];
    const float* W3      = (const float*)d_in[5];
    const float* b3      = (const float*)d_in[6];
    float* out = (float*)d_out;
    float* rep = (float*)d_ws;   // [B][600] = 4.92 MB scratch

    gather_reduce_kernel<<<B_, 256, 0, stream>>>(x, lengths, emb, rep);
    mlp8_kernel<<<B_ / 8, 512, 0, stream>>>(rep, W_new, b_new, W3, b3, out);
}